// Round 6
// baseline (73.256 us; speedup 1.0000x reference)
//
#include <hip/hip_runtime.h>

#define NN 100000
#define NE 600000
#define D 128
#define CW 16          // packed count words per node (125 x 4-bit)

// workspace byte offsets
#define OFF_CNTBF  6400000   // [NN][16] bf16 marginals (3.2 MB)
#define OFF_WSPLIT 9600000   // [2][128][128] bf16 W hi/lo (64 KB)
#define OFF_EFRAG  9665536   // [2][8][64][8] bf16 E^T A-frags (16 KB)

typedef __attribute__((ext_vector_type(8))) short bf16x8;
typedef __attribute__((ext_vector_type(4))) float f32x4;

__device__ __forceinline__ unsigned short f2bf(float x) {
    unsigned u = __float_as_uint(x);
    u += 0x7FFFu + ((u >> 16) & 1u);   // RNE
    return (unsigned short)(u >> 16);
}
__device__ __forceinline__ float bf2f(unsigned short s) {
    return __uint_as_float(((unsigned)s) << 16);
}
__device__ __forceinline__ unsigned pack2(unsigned short a, unsigned short b) {
    return (unsigned)a | ((unsigned)b << 16);
}

// ---------------------------------------------------------------------------
// prep: zero counts + W hi/lo split + E^T MFMA A-fragments (d-permuted)
// ---------------------------------------------------------------------------
__global__ __launch_bounds__(256) void prep_kernel(const float* __restrict__ W,
                                                   const float* __restrict__ emb,
                                                   unsigned char* __restrict__ ws) {
    int bid = blockIdx.x;
    if (bid < 1563) {
        int c = bid * 256 + threadIdx.x;            // int4 index into counts
        if (c < 400000) reinterpret_cast<int4*>(ws)[c] = make_int4(0, 0, 0, 0);
    } else if (bid < 1627) {
        int idx = (bid - 1563) * 256 + threadIdx.x; // 0..16383
        float w = W[idx];
        unsigned short hi = f2bf(w);
        unsigned short lo = f2bf(w - bf2f(hi));
        unsigned short* wsplit = (unsigned short*)(ws + OFF_WSPLIT);
        wsplit[idx] = hi;
        wsplit[16384 + idx] = lo;
    } else {
        int i = (bid - 1627) * 256 + threadIdx.x;   // 0..4095 : [t][lane][e]
        int e = i & 7, l = (i >> 3) & 63, t = (i >> 9) & 7;
        int r = l & 15, lg = l >> 4;
        int j = lg * 8 + e;
        int d = 32 * (t >> 1) + 8 * (r >> 2) + 4 * (t & 1) + (r & 3);
        float v = 0.0f;
        if (j < 15) v = emb[((j / 5) * 8 + (j % 5)) * D + d];
        unsigned short hi = f2bf(v);
        unsigned short lo = f2bf(v - bf2f(hi));
        unsigned short* ef = (unsigned short*)(ws + OFF_EFRAG);
        ef[i] = hi;
        ef[4096 + i] = lo;
    }
}

// ---------------------------------------------------------------------------
// hist: ONE packed atomic per edge (combo = f0*25+f1*5+f2, 4-bit counters)
// ---------------------------------------------------------------------------
__global__ __launch_bounds__(256) void hist_kernel(const int* __restrict__ ef,
                                                   const int* __restrict__ dst,
                                                   unsigned* __restrict__ counts) {
    int g = blockIdx.x * 256 + threadIdx.x;        // 4-edge group
    if (g >= NE / 4) return;
    int4 d4 = reinterpret_cast<const int4*>(dst)[g];
    int4 f0 = reinterpret_cast<const int4*>(ef)[g * 3 + 0];
    int4 f1 = reinterpret_cast<const int4*>(ef)[g * 3 + 1];
    int4 f2 = reinterpret_cast<const int4*>(ef)[g * 3 + 2];
    int fa[12] = {f0.x, f0.y, f0.z, f0.w, f1.x, f1.y, f1.z, f1.w,
                  f2.x, f2.y, f2.z, f2.w};
    int dd[4] = {d4.x, d4.y, d4.z, d4.w};
    #pragma unroll
    for (int i = 0; i < 4; ++i) {
        int combo = fa[i * 3] * 25 + fa[i * 3 + 1] * 5 + fa[i * 3 + 2];
        atomicAdd(counts + dd[i] * CW + (combo >> 3), 1u << ((combo & 7) * 4));
    }
}

// ---------------------------------------------------------------------------
// expand: unpack 125 combo nibbles -> 15 bf16 marginals (+pad), frag order
// ---------------------------------------------------------------------------
__global__ __launch_bounds__(256) void expand_kernel(const unsigned* __restrict__ counts,
                                                     unsigned short* __restrict__ cntbf) {
    int n = blockIdx.x * 256 + threadIdx.x;
    if (n >= NN) return;
    const unsigned* row = counts + n * CW;
    unsigned wd[16];
    #pragma unroll
    for (int i = 0; i < 4; ++i) {
        uint4 v = reinterpret_cast<const uint4*>(row)[i];
        wd[i * 4] = v.x; wd[i * 4 + 1] = v.y; wd[i * 4 + 2] = v.z; wd[i * 4 + 3] = v.w;
    }
    int mi[15];
    #pragma unroll
    for (int j = 0; j < 15; ++j) mi[j] = 0;
    #pragma unroll
    for (int c = 0; c < 125; ++c) {
        int cnt = (int)((wd[c >> 3] >> ((c & 7) * 4)) & 0xFu);
        mi[c / 25] += cnt;
        mi[5 + (c / 5) % 5] += cnt;
        mi[10 + c % 5] += cnt;
    }
    unsigned short o[16];
    #pragma unroll
    for (int j = 0; j < 15; ++j) o[j] = f2bf((float)mi[j]);  // exact (<256)
    o[15] = 0;
    uint4 u;
    u.x = pack2(o[0], o[1]);   u.y = pack2(o[2], o[3]);
    u.z = pack2(o[4], o[5]);   u.w = pack2(o[6], o[7]);
    reinterpret_cast<uint4*>(cntbf + n * 16)[0] = u;
    u.x = pack2(o[8], o[9]);   u.y = pack2(o[10], o[11]);
    u.z = pack2(o[12], o[13]); u.w = pack2(o[14], o[15]);
    reinterpret_cast<uint4*>(cntbf + n * 16)[1] = u;
}

// ---------------------------------------------------------------------------
// fused v6: A through LDS (lane-linear, conflict-free), B (W hi/lo) in
// registers straight from L2 — NO W staging, NO sW LDS.
//   phase1 (wave w, its 16 nodes): S^T = E^T@cnt^T (16 MFMA) -> afrag = bf16(h*S)
//           -> ds_write lane-linear into sA[w][kk][lane]
//   phase2 (wave = (nh = w>>2, cq = w&3)): 64 nodes x 32 cols;
//           per kk: 4 B-frag loads from global wsplit (L2-hot) +
//                   4 lane-linear ds_read_b128 (A) + 16 MFMA
// Block 512 = 8 waves; 128 nodes/block; LDS 32 KB; single barrier.
// ---------------------------------------------------------------------------
__global__ __launch_bounds__(512, 4) void fused_kernel(
        const float* __restrict__ h,
        const unsigned short* __restrict__ cntbf,
        const unsigned short* __restrict__ efrag,
        const unsigned short* __restrict__ wsplit,
        const float* __restrict__ b,
        float* __restrict__ out) {
    __shared__ unsigned short sA[128 * 128];       // 32768 B: [ng][kk][lane]16B

    const int tid  = threadIdx.x;
    const int lane = tid & 63;
    const int w    = tid >> 6;
    const int n0   = blockIdx.x * 128;
    const int lr   = lane & 15;
    const int lg   = lane >> 4;
    char* sAb = (char*)sA;

    // --- phase 1: this wave's 16 nodes, all d ---
    const int node  = n0 + w * 16 + lr;
    const bool valid = node < NN;

    float hv[4][8];
    #pragma unroll
    for (int kk = 0; kk < 4; ++kk) {
        if (valid) {
            float4 h0 = *reinterpret_cast<const float4*>(h + node * D + kk * 32 + lg * 8);
            float4 h1 = *reinterpret_cast<const float4*>(h + node * D + kk * 32 + lg * 8 + 4);
            hv[kk][0] = h0.x; hv[kk][1] = h0.y; hv[kk][2] = h0.z; hv[kk][3] = h0.w;
            hv[kk][4] = h1.x; hv[kk][5] = h1.y; hv[kk][6] = h1.z; hv[kk][7] = h1.w;
        } else {
            #pragma unroll
            for (int e = 0; e < 8; ++e) hv[kk][e] = 0.0f;
        }
    }

    bf16x8 cfrag = {0, 0, 0, 0, 0, 0, 0, 0};
    if (valid && lg < 2)
        cfrag = *reinterpret_cast<const bf16x8*>(cntbf + node * 16 + lg * 8);

    f32x4 s[8];
    #pragma unroll
    for (int t = 0; t < 8; ++t) { f32x4 z = {0, 0, 0, 0}; s[t] = z; }
    #pragma unroll
    for (int p = 0; p < 2; ++p) {
        #pragma unroll
        for (int t = 0; t < 8; ++t) {
            bf16x8 ef = *reinterpret_cast<const bf16x8*>(efrag + p * 4096 + t * 512 + lane * 8);
            s[t] = __builtin_amdgcn_mfma_f32_16x16x32_bf16(ef, cfrag, s[t], 0, 0, 0);
        }
    }

    // pack A-fragments and publish lane-linear (conflict-free ds_write_b128)
    #pragma unroll
    for (int kk = 0; kk < 4; ++kk) {
        unsigned short o[8];
        #pragma unroll
        for (int e = 0; e < 8; ++e)
            o[e] = f2bf(hv[kk][e] * s[kk * 2 + (e >> 2)][e & 3]);
        uint4 uo;
        uo.x = pack2(o[0], o[1]); uo.y = pack2(o[2], o[3]);
        uo.z = pack2(o[4], o[5]); uo.w = pack2(o[6], o[7]);
        *reinterpret_cast<uint4*>(sAb + w * 4096 + kk * 1024 + lane * 16) = uo;
    }
    __syncthreads();

    // --- phase 2: wave (nh, cq): nodes [nh*64, +64), cols [cq*32, +32) ---
    const int nh = w >> 2;
    const int cq = w & 3;

    f32x4 acc[4][2];
    #pragma unroll
    for (int j = 0; j < 2; ++j) {
        float bv = b[cq * 32 + j * 16 + lr];
        f32x4 t = {bv, bv, bv, bv};
        #pragma unroll
        for (int i = 0; i < 4; ++i) acc[i][j] = t;
    }

    #pragma unroll
    for (int kk = 0; kk < 4; ++kk) {
        // B fragments (hi/lo) from global (L2-hot 64 KB array)
        bf16x8 bh[2], bl[2];
        #pragma unroll
        for (int j = 0; j < 2; ++j) {
            int col = cq * 32 + j * 16 + lr;
            const unsigned short* bp = wsplit + col * 128 + kk * 32 + lg * 8;
            bh[j] = *reinterpret_cast<const bf16x8*>(bp);
            bl[j] = *reinterpret_cast<const bf16x8*>(bp + 16384);
        }
        // A slices, lane-linear ds_read_b128
        bf16x8 a[4];
        #pragma unroll
        for (int i = 0; i < 4; ++i)
            a[i] = *reinterpret_cast<const bf16x8*>(
                sAb + (nh * 4 + i) * 4096 + kk * 1024 + lane * 16);
        #pragma unroll
        for (int i = 0; i < 4; ++i) {
            #pragma unroll
            for (int j = 0; j < 2; ++j) {
                acc[i][j] = __builtin_amdgcn_mfma_f32_16x16x32_bf16(a[i], bh[j], acc[i][j], 0, 0, 0);
                acc[i][j] = __builtin_amdgcn_mfma_f32_16x16x32_bf16(a[i], bl[j], acc[i][j], 0, 0, 0);
            }
        }
    }

    // --- store ---
    #pragma unroll
    for (int i = 0; i < 4; ++i) {
        #pragma unroll
        for (int j = 0; j < 2; ++j) {
            int col = cq * 32 + j * 16 + lr;
            #pragma unroll
            for (int r = 0; r < 4; ++r) {
                int n2 = n0 + nh * 64 + i * 16 + lg * 4 + r;
                if (n2 < NN) out[n2 * D + col] = acc[i][j][r];
            }
        }
    }
}

extern "C" void kernel_launch(void* const* d_in, const int* in_sizes, int n_in,
                              void* d_out, int out_size, void* d_ws, size_t ws_size,
                              hipStream_t stream) {
    const float* h   = (const float*)d_in[0];
    const int*   ef  = (const int*)d_in[1];
    const int*   dst = (const int*)d_in[2];
    const float* emb = (const float*)d_in[3];
    const float* W   = (const float*)d_in[4];
    const float* b   = (const float*)d_in[5];
    float*       out = (float*)d_out;

    unsigned char*  ws     = (unsigned char*)d_ws;
    unsigned*       counts = (unsigned*)ws;                         // 6.4 MB
    unsigned short* cntbf  = (unsigned short*)(ws + OFF_CNTBF);     // 3.2 MB
    unsigned short* wsplit = (unsigned short*)(ws + OFF_WSPLIT);    // 64 KB
    unsigned short* efr    = (unsigned short*)(ws + OFF_EFRAG);     // 16 KB

    prep_kernel<<<1563 + 64 + 16, 256, 0, stream>>>(W, emb, ws);
    hist_kernel<<<(NE / 4 + 255) / 256, 256, 0, stream>>>(ef, dst, counts);
    expand_kernel<<<(NN + 255) / 256, 256, 0, stream>>>(counts, cntbf);
    fused_kernel<<<(NN + 127) / 128, 512, 0, stream>>>(h, cntbf, efr, wsplit, b, out);
}